// Round 14
// baseline (211.105 us; speedup 1.0000x reference)
//
#include <hip/hip_runtime.h>
#include <hip/hip_bf16.h>
#include <math.h>

#define HIDDEN 1024
#define NH 16
#define HD 64
#define BATCH 2
#define SEQ 2048

typedef __attribute__((ext_vector_type(8))) short bf16x8;
typedef __attribute__((ext_vector_type(4))) float f32x4;

static __device__ __forceinline__ unsigned short f2b(float f) {
    __hip_bfloat16 h = __float2bfloat16(f);
    return __builtin_bit_cast(unsigned short, h);
}

static __device__ __forceinline__ float fexp2(float x) {
    return __builtin_amdgcn_exp2f(x);   // v_exp_f32, single instruction
}

// async global->LDS, 16B per lane. LDS dest must be wave-uniform base + lane*16.
static __device__ __forceinline__ void async16(const unsigned short* g, unsigned short* l) {
    __builtin_amdgcn_global_load_lds(
        (const __attribute__((address_space(1))) unsigned int*)g,
        (__attribute__((address_space(3))) unsigned int*)l, 16, 0, 0);
}

// ---------------------------------------------------------------------------
// Kernel 0: fp32 -> bf16 conversion of X (4M elems) and Wq/Wk/Wv/Wo (1M each)
// into one contiguous 8M-element bf16 region of ws. 4 elems/thread.
// ---------------------------------------------------------------------------
__global__ __launch_bounds__(256)
void cvt_bf16(const float* __restrict__ X,
              const float* __restrict__ Wq, const float* __restrict__ Wk,
              const float* __restrict__ Wv, const float* __restrict__ Wo,
              unsigned short* __restrict__ dst)
{
    const size_t g = (size_t)blockIdx.x * 256 + threadIdx.x;  // group of 4 elems
    const float* src;
    size_t local;
    if (g < 1048576) {            // X: 4M elems = 1M groups
        src = X; local = g;
    } else {
        const size_t gg = g - 1048576;
        const int r = (int)(gg >> 18);        // 262144 groups per weight
        local = gg & 262143;
        src = (r == 0) ? Wq : ((r == 1) ? Wk : ((r == 2) ? Wv : Wo));
    }
    const float4 v = *(const float4*)(src + local * 4);
    ushort4 o;
    o.x = f2b(v.x); o.y = f2b(v.y); o.z = f2b(v.z); o.w = f2b(v.w);
    *(ushort4*)(dst + g * 4) = o;
}

// ---------------------------------------------------------------------------
// Kernel 1: FUSED q+k+v projection + bias + RoPE. Round-14 restructure:
// one block computes ALL THREE projections for its (tm, head) -- the A tile
// is staged once per k-step and feeds 3 B tiles, so each barrier-drain
// (the structure's dominant cost; W streams from L3) is amortized over
// 48 MFMAs instead of 16, and X total re-reads drop 24x -> 16x (192->128MB).
// Geometry: BM=128, BN=64 (exactly one head), grid (32,16) = 512 blocks =
// 2 blocks/CU exact. LDS = As 16KB + Bs[3] 24KB = 40KB. acc[3][4][2] ~150
// VGPR <= 256 (grid caps residency at 2/CU, so no 128-cliff exposure).
// Per-wave cols: d = j*32 + (wave>>1)*16 + l16 -> d%32 = w2*16+l16 is ONE
// freq per thread (16 sincosf, was 32); RoPE partner d^32 = frag j^1;
// sign -/+ for j=0/1 (rotate_half). q,k share the same sincos.
// Staging keeps the proven pattern: linear LDS dest + inverse-swizzled
// global source (slot (row,cc) holds chunk cc^(row&7)); reads XOR same term.
// ---------------------------------------------------------------------------
__global__ __launch_bounds__(256, 2)
void qkv_rope(const unsigned short* __restrict__ X,
              const unsigned short* __restrict__ Wqb, const float* __restrict__ bq,
              const unsigned short* __restrict__ Wkb, const float* __restrict__ bk,
              const unsigned short* __restrict__ Wvb, const float* __restrict__ bv,
              unsigned short* __restrict__ qw, unsigned short* __restrict__ kw,
              unsigned short* __restrict__ vw)
{
    const int tn = blockIdx.y * 64;          // head-aligned 64-col tile
    const int h  = blockIdx.y;
    const int tm = blockIdx.x * 128;

    __shared__ __align__(16) unsigned short As[128 * 64];      // 16 KB
    __shared__ __align__(16) unsigned short Bs[3][64 * 64];    // 24 KB

    const int tid  = threadIdx.x;
    const int lane = tid & 63;
    const int wave = tid >> 6;
    const int quad = lane >> 4;
    const int l16  = lane & 15;
    const int wm   = (wave & 1) * 64;        // M half
    const int w2   = wave >> 1;              // 16-col interleave selector

    // staging geometry: thread owns LDS slot (row = tid>>3 + 32p, cc = tid&7);
    // source col-chunk = cc ^ (row&7)  (row&7 == (tid>>3)&7, p*32 = 0 mod 8)
    const int srow = tid >> 3;               // 0..31
    const int sccx = (tid & 7) ^ (srow & 7);
    const unsigned short* Ag  = X   + (size_t)(tm + srow) * HIDDEN + sccx * 8;
    const unsigned short* Bg0 = Wqb + (size_t)(tn + srow) * HIDDEN + sccx * 8;
    const unsigned short* Bg1 = Wkb + (size_t)(tn + srow) * HIDDEN + sccx * 8;
    const unsigned short* Bg2 = Wvb + (size_t)(tn + srow) * HIDDEN + sccx * 8;
    unsigned short* lA = As + tid * 8;

    f32x4 acc[3][4][2] = {};   // [proj][i][j], all indices compile-time const

    for (int k0 = 0; k0 < HIDDEN; k0 += 64) {
        __syncthreads();
#pragma unroll
        for (int p = 0; p < 4; ++p)
            async16(Ag + k0 + p * 32 * HIDDEN, lA + p * 2048);
#pragma unroll
        for (int p = 0; p < 2; ++p) {
            async16(Bg0 + k0 + p * 32 * HIDDEN, &Bs[0][tid * 8 + p * 2048]);
            async16(Bg1 + k0 + p * 32 * HIDDEN, &Bs[1][tid * 8 + p * 2048]);
            async16(Bg2 + k0 + p * 32 * HIDDEN, &Bs[2][tid * 8 + p * 2048]);
        }
        __syncthreads();
#pragma unroll
        for (int c = 0; c < 2; ++c) {
            const int csw = ((c * 4 + quad) ^ (l16 & 7)) * 8;   // swizzled k-chunk
            bf16x8 af[4];
#pragma unroll
            for (int i = 0; i < 4; ++i) {
                const int row = wm + i * 16 + l16;
                af[i] = *(const bf16x8*)(As + row * 64 + csw);
            }
#pragma unroll
            for (int pr = 0; pr < 3; ++pr) {
                bf16x8 bfr[2];
#pragma unroll
                for (int j = 0; j < 2; ++j) {
                    const int row = j * 32 + w2 * 16 + l16;
                    bfr[j] = *(const bf16x8*)(&Bs[pr][row * 64 + csw]);
                }
#pragma unroll
                for (int i = 0; i < 4; ++i)
#pragma unroll
                    for (int j = 0; j < 2; ++j)
                        acc[pr][i][j] = __builtin_amdgcn_mfma_f32_16x16x32_bf16(af[i], bfr[j], acc[pr][i][j], 0, 0, 0);
            }
        }
    }

    // Epilogue: bias + RoPE (q,k) + store all three to (B,NH,S,D).
    // d = j*32 + w2*16 + l16; freq idx = d%32 = w2*16+l16 (one per thread);
    // rotate_half partner d^32 = frag j^1; sign: j=0 -> -vp, j=1 -> +vp.
    const float LB = 0.4152410118609203f;   // log2(10000)/32
    const float invf = exp2f(-LB * (float)(w2 * 16 + l16));
    float bsv[3][2];
#pragma unroll
    for (int j = 0; j < 2; ++j) {
        const int n = tn + j * 32 + w2 * 16 + l16;
        bsv[0][j] = bq[n]; bsv[1][j] = bk[n]; bsv[2][j] = bv[n];
    }
#pragma unroll
    for (int i = 0; i < 4; ++i) {
#pragma unroll
        for (int r = 0; r < 4; ++r) {
            const int m = tm + wm + i * 16 + quad * 4 + r;   // C/D row = quad*4+r
            const int b = m >> 11;
            const int s = m & (SEQ - 1);
            float sn, cs;
            __sincosf((float)s * invf, &sn, &cs);
            const size_t obase = (((size_t)(b * NH + h)) * SEQ + s) * HD;
#pragma unroll
            for (int j = 0; j < 2; ++j) {
                const int d = j * 32 + w2 * 16 + l16;
                // q (rope)
                {
                    const float v0 = acc[0][i][j][r] + bsv[0][j];
                    const float vp = acc[0][i][j ^ 1][r] + bsv[0][j ^ 1];
                    qw[obase + d] = f2b(v0 * cs + (j ? vp : -vp) * sn);
                }
                // k (rope)
                {
                    const float v0 = acc[1][i][j][r] + bsv[1][j];
                    const float vp = acc[1][i][j ^ 1][r] + bsv[1][j ^ 1];
                    kw[obase + d] = f2b(v0 * cs + (j ? vp : -vp) * sn);
                }
                // v (plain)
                vw[obase + d] = f2b(acc[2][i][j][r] + bsv[2][j]);
            }
        }
    }
}

// ---------------------------------------------------------------------------
// Kernel 2: flash attention. grid (16 q-tiles, 32 b*h), block 256 (4 waves).
// UNCHANGED (control). dbuf Vt, 1 barrier/tile, XCD remap, Vt XOR swizzle,
// shuffle-free log2 softmax (lane-local defer-max gate + lane-partial l),
// VGPR 120 <= 128 for 2 blocks/CU.
// ---------------------------------------------------------------------------
__global__ __launch_bounds__(256, 2)
void attn_fwd(const unsigned short* __restrict__ qb, const unsigned short* __restrict__ kb,
              const unsigned short* __restrict__ vb, unsigned short* __restrict__ ob)
{
    // XCD-aware remap: 512 blocks = 8 XCDs * 64. Each XCD gets 4 consecutive
    // (b,h) pairs (all 16 q-tiles of a head on one XCD -> K/V L2-resident).
    const int flat  = blockIdx.y * gridDim.x + blockIdx.x;  // dispatch-linear
    const int flat2 = (flat & 7) * 64 + (flat >> 3);        // bijective, 512=8*64
    const int bh = flat2 >> 4;
    const int qt = flat2 & 15;
    const int b  = bh >> 4;
    const int h  = bh & 15;
    const unsigned short* Q = qb + (size_t)bh * SEQ * HD;
    const unsigned short* K = kb + (size_t)bh * SEQ * HD;
    const unsigned short* V = vb + (size_t)bh * SEQ * HD;

    const int tid  = threadIdx.x;
    const int wave = tid >> 6;
    const int lane = tid & 63;
    const int quad = lane >> 4;
    const int l16  = lane & 15;
    const int q0   = qt * 128 + wave * 32;

    __shared__ __align__(16) unsigned short Pb[4][32 * 136];  // per-wave P, stride 136
    __shared__ __align__(16) unsigned short Vt[2][64 * 136];  // dbuf V^T, swizzled cols

    // Q fragments (A operand): held in registers for all K tiles
    bf16x8 qf[2][2];
#pragma unroll
    for (int mt = 0; mt < 2; ++mt)
#pragma unroll
        for (int kk = 0; kk < 2; ++kk)
            qf[mt][kk] = *(const bf16x8*)(Q + (size_t)(q0 + mt * 16 + l16) * HD + kk * 32 + quad * 8);

    f32x4 oacc[2][4] = {};
    float mr[2][4], lr[2][4];
#pragma unroll
    for (int mt = 0; mt < 2; ++mt)
#pragma unroll
        for (int r = 0; r < 4; ++r) { mr[mt][r] = -3.0e38f; lr[mt][r] = 0.f; }

    // V staging geometry: thread loads V[t0+vkey+32p][vd0..vd0+7], scatters
    // transposed with column swizzle ky ^ (vm<<3) (vm = (d>>3)&7, constant).
    const int vkey = tid >> 3;          // 0..31
    const int vd0  = (tid & 7) * 8;
    const int vm   = tid & 7;

    const float KSCL = 0.18033688011112042f;  // 0.125 * log2(e)

    for (int kt = 0; kt < SEQ / 128; ++kt) {
        const int t0  = kt * 128;
        const int buf = kt & 1;

        // S = Q K^T for this tile
        f32x4 sc[2][8] = {};
#pragma unroll
        for (int kk = 0; kk < 2; ++kk) {
            bf16x8 kf[8];
#pragma unroll
            for (int jj = 0; jj < 8; ++jj)
                kf[jj] = *(const bf16x8*)(K + (size_t)(t0 + jj * 16 + l16) * HD + kk * 32 + quad * 8);
#pragma unroll
            for (int mt = 0; mt < 2; ++mt)
#pragma unroll
                for (int jj = 0; jj < 8; ++jj)
                    sc[mt][jj] = __builtin_amdgcn_mfma_f32_16x16x32_bf16(qf[mt][kk], kf[jj], sc[mt][jj], 0, 0, 0);
        }

        // V load + V^T scatter into Vt[buf] (no barrier needed before:
        // buf(t) was last read at PV(t-2), separated by barrier(t-1)).
#pragma unroll
        for (int p = 0; p < 4; ++p) {
            const int ky = vkey + 32 * p;
            const int cs = ky ^ (vm << 3);
            bf16x8 vv = *(const bf16x8*)(V + (size_t)(t0 + ky) * HD + vd0);
#pragma unroll
            for (int u = 0; u < 8; ++u)
                Vt[buf][(vd0 + u) * 136 + cs] = ((const unsigned short*)&vv)[u];
        }

        // ---- online softmax, log2 domain, shuffle-free steady state ----
        // dmax = max over this thread's 8 row-slots of (lane-local max - mold).
        // __all(dmax<=8) over 64 lanes <=> every row's true max within 8 of
        // its running max -> keep mold: no rescale, no cross-lane reduce.
        float dmax = -3.0e38f;
#pragma unroll
        for (int mt = 0; mt < 2; ++mt) {
#pragma unroll
            for (int r = 0; r < 4; ++r) {
                float mx = sc[mt][0][r];
#pragma unroll
                for (int jj = 1; jj < 8; ++jj) mx = fmaxf(mx, sc[mt][jj][r]);
                dmax = fmaxf(dmax, fmaf(mx, KSCL, -mr[mt][r]));
            }
        }
        if (!__all(dmax <= 8.0f)) {     // rare: first tile + occasional growth
#pragma unroll
            for (int mt = 0; mt < 2; ++mt) {
#pragma unroll
                for (int r = 0; r < 4; ++r) {
                    float mx = sc[mt][0][r];
#pragma unroll
                    for (int jj = 1; jj < 8; ++jj) mx = fmaxf(mx, sc[mt][jj][r]);
                    float ms = mx * KSCL;
#pragma unroll
                    for (int off = 8; off; off >>= 1) ms = fmaxf(ms, __shfl_xor(ms, off));
                    const float mnew  = fmaxf(mr[mt][r], ms);
                    const float alpha = fexp2(mr[mt][r] - mnew);
                    mr[mt][r] = mnew;
                    lr[mt][r] *= alpha;
#pragma unroll
                    for (int nn = 0; nn < 4; ++nn) oacc[mt][nn][r] *= alpha;
                }
            }
        }
        // P = exp2(s*KSCL - m); lr accumulates LANE-PARTIAL sums
#pragma unroll
        for (int mt = 0; mt < 2; ++mt) {
#pragma unroll
            for (int r = 0; r < 4; ++r) {
                const float mnew = mr[mt][r];
                float ps = 0.f;
                const int prow = (mt * 16 + quad * 4 + r) * 136;
#pragma unroll
                for (int jj = 0; jj < 8; ++jj) {
                    const float p = fexp2(fmaf(sc[mt][jj][r], KSCL, -mnew));
                    ps += p;
                    Pb[wave][prow + jj * 16 + l16] = f2b(p);
                }
                lr[mt][r] += ps;
            }
        }

        __syncthreads();  // Vt[buf] writes visible to all waves

        // O += P V   (A = P from LDS, B = swizzled V^T from LDS)
#pragma unroll
        for (int kk2 = 0; kk2 < 4; ++kk2) {
            bf16x8 pf[2], vf[4];
#pragma unroll
            for (int mt = 0; mt < 2; ++mt)
                pf[mt] = *(const bf16x8*)(&Pb[wave][(mt * 16 + l16) * 136 + kk2 * 32 + quad * 8]);
#pragma unroll
            for (int nn = 0; nn < 4; ++nn) {
                const int d   = nn * 16 + l16;
                const int mrd = (nn * 2 + (l16 >> 3)) & 7;               // (d>>3)&7
                const int cb  = (kk2 * 32 + quad * 8) ^ (mrd << 3);      // swizzled col base
                vf[nn] = *(const bf16x8*)(&Vt[buf][d * 136 + cb]);
            }
#pragma unroll
            for (int mt = 0; mt < 2; ++mt)
#pragma unroll
                for (int nn = 0; nn < 4; ++nn)
                    oacc[mt][nn] = __builtin_amdgcn_mfma_f32_16x16x32_bf16(pf[mt], vf[nn], oacc[mt][nn], 0, 0, 0);
        }
    }

    // reduce lane-partial l across the row's 16 lanes, normalize, store
#pragma unroll
    for (int mt = 0; mt < 2; ++mt) {
#pragma unroll
        for (int r = 0; r < 4; ++r) {
            float ls = lr[mt][r];
#pragma unroll
            for (int off = 8; off; off >>= 1) ls += __shfl_xor(ls, off);
            const float inv = 1.0f / ls;
            const int s = q0 + mt * 16 + quad * 4 + r;
#pragma unroll
            for (int nn = 0; nn < 4; ++nn) {
                const int d = nn * 16 + l16;
                ob[((size_t)(b * SEQ + s)) * HIDDEN + h * HD + d] = f2b(oacc[mt][nn][r] * inv);
            }
        }
    }
}

// ---------------------------------------------------------------------------
// Kernel 3: output projection GEMM + fp32 bias. 64x64 tiles, grid (64,16)
// = 1024 blocks = 4 blocks/CU (round-11 bisect confirmed -2.8us).
// LDS 16KB, acc[2][2], launch_bounds(256,4). Output FP32.
// ---------------------------------------------------------------------------
__global__ __launch_bounds__(256, 4)
void out_proj(const unsigned short* __restrict__ A,
              const unsigned short* __restrict__ W,
              const float* __restrict__ bias,
              float* __restrict__ out)
{
    const int tn = blockIdx.y * 64;
    const int tm = blockIdx.x * 64;

    __shared__ __align__(16) unsigned short As[64 * 64];    // 8 KB
    __shared__ __align__(16) unsigned short Bs[64 * 64];    // 8 KB

    const int tid  = threadIdx.x;
    const int lane = tid & 63;
    const int wave = tid >> 6;
    const int quad = lane >> 4;
    const int l16  = lane & 15;
    const int wm   = (wave & 1) * 32;
    const int wn   = (wave >> 1) * 32;

    const int srow = tid >> 3;           // 0..31
    const int sccx = (tid & 7) ^ (srow & 7);
    const unsigned short* Ag = A + (size_t)(tm + srow) * HIDDEN + sccx * 8;
    const unsigned short* Bg = W + (size_t)(tn + srow) * HIDDEN + sccx * 8;
    unsigned short* lA = As + tid * 8;
    unsigned short* lB = Bs + tid * 8;

    f32x4 acc[2][2] = {};

    for (int k0 = 0; k0 < HIDDEN; k0 += 64) {
        __syncthreads();
#pragma unroll
        for (int p = 0; p < 2; ++p) {
            async16(Ag + k0 + p * 32 * HIDDEN, lA + p * 2048);
            async16(Bg + k0 + p * 32 * HIDDEN, lB + p * 2048);
        }
        __syncthreads();
#pragma unroll
        for (int c = 0; c < 2; ++c) {
            bf16x8 af[2], bfr[2];
#pragma unroll
            for (int i = 0; i < 2; ++i) {
                const int row = wm + i * 16 + l16;
                af[i] = *(const bf16x8*)(As + row * 64 + (((c * 4 + quad) ^ (l16 & 7)) * 8));
            }
#pragma unroll
            for (int j = 0; j < 2; ++j) {
                const int row = wn + j * 16 + l16;
                bfr[j] = *(const bf16x8*)(Bs + row * 64 + (((c * 4 + quad) ^ (l16 & 7)) * 8));
            }
#pragma unroll
            for (int i = 0; i < 2; ++i)
#pragma unroll
                for (int j = 0; j < 2; ++j)
                    acc[i][j] = __builtin_amdgcn_mfma_f32_16x16x32_bf16(af[i], bfr[j], acc[i][j], 0, 0, 0);
        }
    }

    float bsv[2];
#pragma unroll
    for (int j = 0; j < 2; ++j) bsv[j] = bias[tn + wn + j * 16 + l16];
#pragma unroll
    for (int i = 0; i < 2; ++i) {
#pragma unroll
        for (int r = 0; r < 4; ++r) {
            const int m = tm + wm + i * 16 + quad * 4 + r;
#pragma unroll
            for (int j = 0; j < 2; ++j) {
                const int n = tn + wn + j * 16 + l16;
                out[(size_t)m * HIDDEN + n] = acc[i][j][r] + bsv[j];   // fp32 output
            }
        }
    }
}

extern "C" void kernel_launch(void* const* d_in, const int* in_sizes, int n_in,
                              void* d_out, int out_size, void* d_ws, size_t ws_size,
                              hipStream_t stream) {
    // Inputs fp32 (setup_inputs uses dtype=jnp.float32); output fp32.
    const float* hs = (const float*)d_in[0];
    const float* Wq = (const float*)d_in[1];
    const float* bq = (const float*)d_in[2];
    const float* Wk = (const float*)d_in[3];
    const float* bk = (const float*)d_in[4];
    const float* Wv = (const float*)d_in[5];
    const float* bv = (const float*)d_in[6];
    const float* Wo = (const float*)d_in[7];
    const float* bo = (const float*)d_in[8];
    float* out = (float*)d_out;

    // ws layout (bf16 elements): Xb[4M] Wqb[1M] Wkb[1M] Wvb[1M] Wob[1M]
    //                            qw[4M] kw[4M] vw[4M] aw[4M]  = 48 MB total
    unsigned short* Xb  = (unsigned short*)d_ws;
    unsigned short* Wqb = Xb + 4194304;
    unsigned short* Wkb = Wqb + 1048576;
    unsigned short* Wvb = Wkb + 1048576;
    unsigned short* Wob = Wvb + 1048576;
    unsigned short* qw  = Wob + 1048576;
    unsigned short* kw  = qw + 4194304;
    unsigned short* vw  = kw + 4194304;
    unsigned short* aw  = vw + 4194304;

    cvt_bf16<<<dim3(8192), 256, 0, stream>>>(hs, Wq, Wk, Wv, Wo, Xb);
    qkv_rope<<<dim3(32, 16), 256, 0, stream>>>(Xb, Wqb, bq, Wkb, bk, Wvb, bv, qw, kw, vw);
    attn_fwd<<<dim3(16, 32), 256, 0, stream>>>(qw, kw, vw, aw);
    out_proj<<<dim3(64, 16), 256, 0, stream>>>(aw, Wob, bo, out);
}

// Round 15
// 207.227 us; speedup vs baseline: 1.0187x; 1.0187x over previous
//
#include <hip/hip_runtime.h>
#include <hip/hip_bf16.h>
#include <math.h>

#define HIDDEN 1024
#define NH 16
#define HD 64
#define BATCH 2
#define SEQ 2048

typedef __attribute__((ext_vector_type(8))) short bf16x8;
typedef __attribute__((ext_vector_type(4))) float f32x4;

static __device__ __forceinline__ unsigned short f2b(float f) {
    __hip_bfloat16 h = __float2bfloat16(f);
    return __builtin_bit_cast(unsigned short, h);
}

static __device__ __forceinline__ float fexp2(float x) {
    return __builtin_amdgcn_exp2f(x);   // v_exp_f32, single instruction
}

// async global->LDS, 16B per lane. LDS dest must be wave-uniform base + lane*16.
static __device__ __forceinline__ void async16(const unsigned short* g, unsigned short* l) {
    __builtin_amdgcn_global_load_lds(
        (const __attribute__((address_space(1))) unsigned int*)g,
        (__attribute__((address_space(3))) unsigned int*)l, 16, 0, 0);
}

// ---------------------------------------------------------------------------
// Kernel 0: fp32 -> bf16 conversion of X (4M elems) and Wq/Wk/Wv/Wo (1M each)
// into one contiguous 8M-element bf16 region of ws. 4 elems/thread.
// (At its own roofline: 72MB @ ~6.3TB/s ~= 11us floor.)
// ---------------------------------------------------------------------------
__global__ __launch_bounds__(256)
void cvt_bf16(const float* __restrict__ X,
              const float* __restrict__ Wq, const float* __restrict__ Wk,
              const float* __restrict__ Wv, const float* __restrict__ Wo,
              unsigned short* __restrict__ dst)
{
    const size_t g = (size_t)blockIdx.x * 256 + threadIdx.x;  // group of 4 elems
    const float* src;
    size_t local;
    if (g < 1048576) {            // X: 4M elems = 1M groups
        src = X; local = g;
    } else {
        const size_t gg = g - 1048576;
        const int r = (int)(gg >> 18);        // 262144 groups per weight
        local = gg & 262143;
        src = (r == 0) ? Wq : ((r == 1) ? Wk : ((r == 2) ? Wv : Wo));
    }
    const float4 v = *(const float4*)(src + local * 4);
    ushort4 o;
    o.x = f2b(v.x); o.y = f2b(v.y); o.z = f2b(v.z); o.w = f2b(v.w);
    *(ushort4*)(dst + g * 4) = o;
}

// ---------------------------------------------------------------------------
// Kernel 1: fused QKV projection + bias + RoPE. VERIFIED-BEST CONFIG
// (208.7us total, round 11; replayed 209.6 round 13). 128x128 tiles, grid
// (32,24) = 768 = 3 blocks/CU, BK=64, 2-barrier global_load_lds staging.
// Structural attacks on this loop all failed and were reverted:
//  - r10 64x128 retile: +50% staging bytes > extra TLP (-3us)
//  - r12 A-direct + B-dbuf: vmcnt is one shared counter -> waiting on the
//    younger A loads forced vmcnt(0), draining the B prefetch (-30us)
//  - r14 q+k+v fusion: 3x MFMA/drain exactly offset by 3->2 blocks/CU (~0)
// Past this structure requires counted-vmcnt asm + raw s_barrier (T4).
// Linear map is XCD-localized for X (for fixed x, all 24 y-blocks on XCD
// x&7 -> 1MB X chunk read 24x from own L2). Staging: linear LDS dest +
// inverse-swizzled global source (slot (row,cc) holds chunk cc^(row&7));
// reads XOR the same term (<=2-way conflicts = free).
// ---------------------------------------------------------------------------
__global__ __launch_bounds__(256, 3)
void qkv_rope(const unsigned short* __restrict__ X,
              const unsigned short* __restrict__ Wqb, const float* __restrict__ bq,
              const unsigned short* __restrict__ Wkb, const float* __restrict__ bk,
              const unsigned short* __restrict__ Wvb, const float* __restrict__ bv,
              unsigned short* __restrict__ qw, unsigned short* __restrict__ kw,
              unsigned short* __restrict__ vw)
{
    const int proj = blockIdx.y >> 3;
    const unsigned short* W = (proj == 0) ? Wqb : ((proj == 1) ? Wkb : Wvb);
    const float* bias       = (proj == 0) ? bq : ((proj == 1) ? bk : bv);
    unsigned short* outp    = (proj == 0) ? qw : ((proj == 1) ? kw : vw);
    const int tn = (blockIdx.y & 7) * 128;
    const int tm = blockIdx.x * 128;

    __shared__ __align__(16) unsigned short As[128 * 64];   // 16 KB
    __shared__ __align__(16) unsigned short Bs[128 * 64];   // 16 KB

    const int tid  = threadIdx.x;
    const int lane = tid & 63;
    const int wave = tid >> 6;
    const int quad = lane >> 4;
    const int l16  = lane & 15;
    const int wm   = (wave & 1) * 64;
    const int wn   = (wave >> 1) * 64;

    // staging geometry: thread owns LDS slot (row = tid>>3 + 32p, cc = tid&7);
    // source col-chunk = cc ^ (row&7)  (row&7 == (tid>>3)&7, p*32 = 0 mod 8)
    const int srow = tid >> 3;           // 0..31
    const int sccx = (tid & 7) ^ (srow & 7);
    const unsigned short* Ag = X + (size_t)(tm + srow) * HIDDEN + sccx * 8;
    const unsigned short* Bg = W + (size_t)(tn + srow) * HIDDEN + sccx * 8;
    unsigned short* lA = As + tid * 8;
    unsigned short* lB = Bs + tid * 8;

    f32x4 acc[4][4] = {};

    for (int k0 = 0; k0 < HIDDEN; k0 += 64) {
        __syncthreads();
#pragma unroll
        for (int p = 0; p < 4; ++p) {
            async16(Ag + k0 + p * 32 * HIDDEN, lA + p * 2048);
            async16(Bg + k0 + p * 32 * HIDDEN, lB + p * 2048);
        }
        __syncthreads();
#pragma unroll
        for (int c = 0; c < 2; ++c) {
            bf16x8 af[4], bfr[4];
#pragma unroll
            for (int i = 0; i < 4; ++i) {
                const int row = wm + i * 16 + l16;
                af[i] = *(const bf16x8*)(As + row * 64 + (((c * 4 + quad) ^ (l16 & 7)) * 8));
            }
#pragma unroll
            for (int j = 0; j < 4; ++j) {
                const int row = wn + j * 16 + l16;
                bfr[j] = *(const bf16x8*)(Bs + row * 64 + (((c * 4 + quad) ^ (l16 & 7)) * 8));
            }
#pragma unroll
            for (int i = 0; i < 4; ++i)
#pragma unroll
                for (int j = 0; j < 4; ++j)
                    acc[i][j] = __builtin_amdgcn_mfma_f32_16x16x32_bf16(af[i], bfr[j], acc[i][j], 0, 0, 0);
        }
    }

    // Epilogue: bias + RoPE + store to (B,NH,S,D).
    // Within a wave the 64 cols are exactly one head; partner d^32 = frag j^2.
    const bool dorope = (proj < 2);
    float bsv[4];
#pragma unroll
    for (int j = 0; j < 4; ++j) bsv[j] = bias[tn + wn + j * 16 + l16];
    float inv_e = 0.f, inv_o = 0.f;
    if (dorope) {
        // 10000^(-f/32) = 2^(-f*log2(10000)/32); log2(10000)/32 = 0.41524101186...
        const float LB = 0.4152410118609203f;
        inv_e = exp2f(-LB * (float)l16);          // freq idx = l16      (j even)
        inv_o = exp2f(-LB * (float)(16 + l16));   // freq idx = 16+l16   (j odd)
    }
#pragma unroll
    for (int i = 0; i < 4; ++i) {
#pragma unroll
        for (int r = 0; r < 4; ++r) {
            const int m = tm + wm + i * 16 + quad * 4 + r;  // C/D row = quad*4+r
            const int b = m >> 11;
            const int s = m & (SEQ - 1);
            float cs0 = 1.f, sn0 = 0.f, cs1 = 1.f, sn1 = 0.f;
            if (dorope) {
                const float sf = (float)s;
                __sincosf(sf * inv_e, &sn0, &cs0);
                __sincosf(sf * inv_o, &sn1, &cs1);
            }
#pragma unroll
            for (int j = 0; j < 4; ++j) {
                const int n = tn + wn + j * 16 + l16;       // C/D col = lane&15
                const float v = acc[i][j][r] + bsv[j];
                float o = v;
                if (dorope) {
                    const float vp = acc[i][j ^ 2][r] + bsv[j ^ 2];
                    o = v * ((j & 1) ? cs1 : cs0) + ((j < 2) ? -vp : vp) * ((j & 1) ? sn1 : sn0);
                }
                const int h = n >> 6;
                const int d = n & 63;
                outp[(((size_t)(b * NH + h)) * SEQ + s) * HD + d] = f2b(o);
            }
        }
    }
}

// ---------------------------------------------------------------------------
// Kernel 2: flash attention. grid (16 q-tiles, 32 b*h), block 256 (4 waves).
// Verified state (~88-94us): dbuf Vt + 1 barrier/tile, XCD remap (FETCH
// 69.7->12.4MB), Vt XOR swizzle (conflicts 17.8M->3.1M), shuffle-free log2
// softmax (lane-local defer-max gate + lane-partial l, zero cross-lane ops
// steady-state), VGPR 120 <= 128 -> 2 blocks/CU (the m69 cliff governs:
// r2/r3 at 136-156 VGPR halved residency and ran 1.6x slower).
// ---------------------------------------------------------------------------
__global__ __launch_bounds__(256, 2)
void attn_fwd(const unsigned short* __restrict__ qb, const unsigned short* __restrict__ kb,
              const unsigned short* __restrict__ vb, unsigned short* __restrict__ ob)
{
    // XCD-aware remap: 512 blocks = 8 XCDs * 64. Each XCD gets 4 consecutive
    // (b,h) pairs (all 16 q-tiles of a head on one XCD -> K/V L2-resident).
    const int flat  = blockIdx.y * gridDim.x + blockIdx.x;  // dispatch-linear
    const int flat2 = (flat & 7) * 64 + (flat >> 3);        // bijective, 512=8*64
    const int bh = flat2 >> 4;
    const int qt = flat2 & 15;
    const int b  = bh >> 4;
    const int h  = bh & 15;
    const unsigned short* Q = qb + (size_t)bh * SEQ * HD;
    const unsigned short* K = kb + (size_t)bh * SEQ * HD;
    const unsigned short* V = vb + (size_t)bh * SEQ * HD;

    const int tid  = threadIdx.x;
    const int wave = tid >> 6;
    const int lane = tid & 63;
    const int quad = lane >> 4;
    const int l16  = lane & 15;
    const int q0   = qt * 128 + wave * 32;

    __shared__ __align__(16) unsigned short Pb[4][32 * 136];  // per-wave P, stride 136
    __shared__ __align__(16) unsigned short Vt[2][64 * 136];  // dbuf V^T, swizzled cols

    // Q fragments (A operand): held in registers for all K tiles
    bf16x8 qf[2][2];
#pragma unroll
    for (int mt = 0; mt < 2; ++mt)
#pragma unroll
        for (int kk = 0; kk < 2; ++kk)
            qf[mt][kk] = *(const bf16x8*)(Q + (size_t)(q0 + mt * 16 + l16) * HD + kk * 32 + quad * 8);

    f32x4 oacc[2][4] = {};
    float mr[2][4], lr[2][4];
#pragma unroll
    for (int mt = 0; mt < 2; ++mt)
#pragma unroll
        for (int r = 0; r < 4; ++r) { mr[mt][r] = -3.0e38f; lr[mt][r] = 0.f; }

    // V staging geometry: thread loads V[t0+vkey+32p][vd0..vd0+7], scatters
    // transposed with column swizzle ky ^ (vm<<3) (vm = (d>>3)&7, constant).
    const int vkey = tid >> 3;          // 0..31
    const int vd0  = (tid & 7) * 8;
    const int vm   = tid & 7;

    const float KSCL = 0.18033688011112042f;  // 0.125 * log2(e)

    for (int kt = 0; kt < SEQ / 128; ++kt) {
        const int t0  = kt * 128;
        const int buf = kt & 1;

        // S = Q K^T for this tile
        f32x4 sc[2][8] = {};
#pragma unroll
        for (int kk = 0; kk < 2; ++kk) {
            bf16x8 kf[8];
#pragma unroll
            for (int jj = 0; jj < 8; ++jj)
                kf[jj] = *(const bf16x8*)(K + (size_t)(t0 + jj * 16 + l16) * HD + kk * 32 + quad * 8);
#pragma unroll
            for (int mt = 0; mt < 2; ++mt)
#pragma unroll
                for (int jj = 0; jj < 8; ++jj)
                    sc[mt][jj] = __builtin_amdgcn_mfma_f32_16x16x32_bf16(qf[mt][kk], kf[jj], sc[mt][jj], 0, 0, 0);
        }

        // V load + V^T scatter into Vt[buf] (no barrier needed before:
        // buf(t) was last read at PV(t-2), separated by barrier(t-1)).
#pragma unroll
        for (int p = 0; p < 4; ++p) {
            const int ky = vkey + 32 * p;
            const int cs = ky ^ (vm << 3);
            bf16x8 vv = *(const bf16x8*)(V + (size_t)(t0 + ky) * HD + vd0);
#pragma unroll
            for (int u = 0; u < 8; ++u)
                Vt[buf][(vd0 + u) * 136 + cs] = ((const unsigned short*)&vv)[u];
        }

        // ---- online softmax, log2 domain, shuffle-free steady state ----
        // dmax = max over this thread's 8 row-slots of (lane-local max - mold).
        // __all(dmax<=8) over 64 lanes <=> every row's true max within 8 of
        // its running max -> keep mold: no rescale, no cross-lane reduce.
        float dmax = -3.0e38f;
#pragma unroll
        for (int mt = 0; mt < 2; ++mt) {
#pragma unroll
            for (int r = 0; r < 4; ++r) {
                float mx = sc[mt][0][r];
#pragma unroll
                for (int jj = 1; jj < 8; ++jj) mx = fmaxf(mx, sc[mt][jj][r]);
                dmax = fmaxf(dmax, fmaf(mx, KSCL, -mr[mt][r]));
            }
        }
        if (!__all(dmax <= 8.0f)) {     // rare: first tile + occasional growth
#pragma unroll
            for (int mt = 0; mt < 2; ++mt) {
#pragma unroll
                for (int r = 0; r < 4; ++r) {
                    float mx = sc[mt][0][r];
#pragma unroll
                    for (int jj = 1; jj < 8; ++jj) mx = fmaxf(mx, sc[mt][jj][r]);
                    float ms = mx * KSCL;
#pragma unroll
                    for (int off = 8; off; off >>= 1) ms = fmaxf(ms, __shfl_xor(ms, off));
                    const float mnew  = fmaxf(mr[mt][r], ms);
                    const float alpha = fexp2(mr[mt][r] - mnew);
                    mr[mt][r] = mnew;
                    lr[mt][r] *= alpha;
#pragma unroll
                    for (int nn = 0; nn < 4; ++nn) oacc[mt][nn][r] *= alpha;
                }
            }
        }
        // P = exp2(s*KSCL - m); lr accumulates LANE-PARTIAL sums
#pragma unroll
        for (int mt = 0; mt < 2; ++mt) {
#pragma unroll
            for (int r = 0; r < 4; ++r) {
                const float mnew = mr[mt][r];
                float ps = 0.f;
                const int prow = (mt * 16 + quad * 4 + r) * 136;
#pragma unroll
                for (int jj = 0; jj < 8; ++jj) {
                    const float p = fexp2(fmaf(sc[mt][jj][r], KSCL, -mnew));
                    ps += p;
                    Pb[wave][prow + jj * 16 + l16] = f2b(p);
                }
                lr[mt][r] += ps;
            }
        }

        __syncthreads();  // Vt[buf] writes visible to all waves

        // O += P V   (A = P from LDS, B = swizzled V^T from LDS)
#pragma unroll
        for (int kk2 = 0; kk2 < 4; ++kk2) {
            bf16x8 pf[2], vf[4];
#pragma unroll
            for (int mt = 0; mt < 2; ++mt)
                pf[mt] = *(const bf16x8*)(&Pb[wave][(mt * 16 + l16) * 136 + kk2 * 32 + quad * 8]);
#pragma unroll
            for (int nn = 0; nn < 4; ++nn) {
                const int d   = nn * 16 + l16;
                const int mrd = (nn * 2 + (l16 >> 3)) & 7;               // (d>>3)&7
                const int cb  = (kk2 * 32 + quad * 8) ^ (mrd << 3);      // swizzled col base
                vf[nn] = *(const bf16x8*)(&Vt[buf][d * 136 + cb]);
            }
#pragma unroll
            for (int mt = 0; mt < 2; ++mt)
#pragma unroll
                for (int nn = 0; nn < 4; ++nn)
                    oacc[mt][nn] = __builtin_amdgcn_mfma_f32_16x16x32_bf16(pf[mt], vf[nn], oacc[mt][nn], 0, 0, 0);
        }
    }

    // reduce lane-partial l across the row's 16 lanes, normalize, store
#pragma unroll
    for (int mt = 0; mt < 2; ++mt) {
#pragma unroll
        for (int r = 0; r < 4; ++r) {
            float ls = lr[mt][r];
#pragma unroll
            for (int off = 8; off; off >>= 1) ls += __shfl_xor(ls, off);
            const float inv = 1.0f / ls;
            const int s = q0 + mt * 16 + quad * 4 + r;
#pragma unroll
            for (int nn = 0; nn < 4; ++nn) {
                const int d = nn * 16 + l16;
                ob[((size_t)(b * SEQ + s)) * HIDDEN + h * HD + d] = f2b(oacc[mt][nn][r] * inv);
            }
        }
    }
}

// ---------------------------------------------------------------------------
// Kernel 3: output projection GEMM + fp32 bias. 64x64 tiles, grid (64,16)
// = 1024 blocks = 4 blocks/CU (round-11 bisect confirmed -2.8us).
// LDS 16KB, acc[2][2], launch_bounds(256,4). Output FP32.
// ---------------------------------------------------------------------------
__global__ __launch_bounds__(256, 4)
void out_proj(const unsigned short* __restrict__ A,
              const unsigned short* __restrict__ W,
              const float* __restrict__ bias,
              float* __restrict__ out)
{
    const int tn = blockIdx.y * 64;
    const int tm = blockIdx.x * 64;

    __shared__ __align__(16) unsigned short As[64 * 64];    // 8 KB
    __shared__ __align__(16) unsigned short Bs[64 * 64];    // 8 KB

    const int tid  = threadIdx.x;
    const int lane = tid & 63;
    const int wave = tid >> 6;
    const int quad = lane >> 4;
    const int l16  = lane & 15;
    const int wm   = (wave & 1) * 32;
    const int wn   = (wave >> 1) * 32;

    const int srow = tid >> 3;           // 0..31
    const int sccx = (tid & 7) ^ (srow & 7);
    const unsigned short* Ag = A + (size_t)(tm + srow) * HIDDEN + sccx * 8;
    const unsigned short* Bg = W + (size_t)(tn + srow) * HIDDEN + sccx * 8;
    unsigned short* lA = As + tid * 8;
    unsigned short* lB = Bs + tid * 8;

    f32x4 acc[2][2] = {};

    for (int k0 = 0; k0 < HIDDEN; k0 += 64) {
        __syncthreads();
#pragma unroll
        for (int p = 0; p < 2; ++p) {
            async16(Ag + k0 + p * 32 * HIDDEN, lA + p * 2048);
            async16(Bg + k0 + p * 32 * HIDDEN, lB + p * 2048);
        }
        __syncthreads();
#pragma unroll
        for (int c = 0; c < 2; ++c) {
            bf16x8 af[2], bfr[2];
#pragma unroll
            for (int i = 0; i < 2; ++i) {
                const int row = wm + i * 16 + l16;
                af[i] = *(const bf16x8*)(As + row * 64 + (((c * 4 + quad) ^ (l16 & 7)) * 8));
            }
#pragma unroll
            for (int j = 0; j < 2; ++j) {
                const int row = wn + j * 16 + l16;
                bfr[j] = *(const bf16x8*)(Bs + row * 64 + (((c * 4 + quad) ^ (l16 & 7)) * 8));
            }
#pragma unroll
            for (int i = 0; i < 2; ++i)
#pragma unroll
                for (int j = 0; j < 2; ++j)
                    acc[i][j] = __builtin_amdgcn_mfma_f32_16x16x32_bf16(af[i], bfr[j], acc[i][j], 0, 0, 0);
        }
    }

    float bsv[2];
#pragma unroll
    for (int j = 0; j < 2; ++j) bsv[j] = bias[tn + wn + j * 16 + l16];
#pragma unroll
    for (int i = 0; i < 2; ++i) {
#pragma unroll
        for (int r = 0; r < 4; ++r) {
            const int m = tm + wm + i * 16 + quad * 4 + r;
#pragma unroll
            for (int j = 0; j < 2; ++j) {
                const int n = tn + wn + j * 16 + l16;
                out[(size_t)m * HIDDEN + n] = acc[i][j][r] + bsv[j];   // fp32 output
            }
        }
    }
}

extern "C" void kernel_launch(void* const* d_in, const int* in_sizes, int n_in,
                              void* d_out, int out_size, void* d_ws, size_t ws_size,
                              hipStream_t stream) {
    // Inputs fp32 (setup_inputs uses dtype=jnp.float32); output fp32.
    const float* hs = (const float*)d_in[0];
    const float* Wq = (const float*)d_in[1];
    const float* bq = (const float*)d_in[2];
    const float* Wk = (const float*)d_in[3];
    const float* bk = (const float*)d_in[4];
    const float* Wv = (const float*)d_in[5];
    const float* bv = (const float*)d_in[6];
    const float* Wo = (const float*)d_in[7];
    const float* bo = (const float*)d_in[8];
    float* out = (float*)d_out;

    // ws layout (bf16 elements): Xb[4M] Wqb[1M] Wkb[1M] Wvb[1M] Wob[1M]
    //                            qw[4M] kw[4M] vw[4M] aw[4M]  = 48 MB total
    unsigned short* Xb  = (unsigned short*)d_ws;
    unsigned short* Wqb = Xb + 4194304;
    unsigned short* Wkb = Wqb + 1048576;
    unsigned short* Wvb = Wkb + 1048576;
    unsigned short* Wob = Wvb + 1048576;
    unsigned short* qw  = Wob + 1048576;
    unsigned short* kw  = qw + 4194304;
    unsigned short* vw  = kw + 4194304;
    unsigned short* aw  = vw + 4194304;

    cvt_bf16<<<dim3(8192), 256, 0, stream>>>(hs, Wq, Wk, Wv, Wo, Xb);
    qkv_rope<<<dim3(32, 24), 256, 0, stream>>>(Xb, Wqb, bq, Wkb, bk, Wvb, bv, qw, kw, vw);
    attn_fwd<<<dim3(16, 32), 256, 0, stream>>>(qw, kw, vw, aw);
    out_proj<<<dim3(64, 16), 256, 0, stream>>>(aw, Wob, bo, out);
}